// Round 8
// baseline (375.845 us; speedup 1.0000x reference)
//
#include <hip/hip_runtime.h>

// B=8, L=512, K=512, D=M=N=P=64, all fp32.
// ws: vkc = 1 MB | kT = 1 MB | grid-barrier counters (8 B)

#define NB 512u   // grid size of fused kernel; 2 blocks/CU exactly (residency!)

__device__ __forceinline__ void lds_barrier() {
    asm volatile("s_waitcnt lgkmcnt(0)" ::: "memory");
    __builtin_amdgcn_s_barrier();
}

// Device-scope sense-reversal grid barrier (Guideline 16: device-scope
// atomics + fences; residency guaranteed by 2-blocks/CU sizing).
__device__ __forceinline__ void grid_barrier(unsigned* cnt, unsigned* gen) {
    __syncthreads();
    __threadfence();                       // make vkc/sc stores device-visible
    if (threadIdx.x == 0) {
        const unsigned g = __hip_atomic_load(gen, __ATOMIC_ACQUIRE,
                                             __HIP_MEMORY_SCOPE_AGENT);
        if (__hip_atomic_fetch_add(cnt, 1u, __ATOMIC_ACQ_REL,
                                   __HIP_MEMORY_SCOPE_AGENT) == NB - 1u) {
            __hip_atomic_store(cnt, 0u, __ATOMIC_RELAXED,
                               __HIP_MEMORY_SCOPE_AGENT);
            __hip_atomic_fetch_add(gen, 1u, __ATOMIC_RELEASE,
                                   __HIP_MEMORY_SCOPE_AGENT);
        } else {
            while (__hip_atomic_load(gen, __ATOMIC_ACQUIRE,
                                     __HIP_MEMORY_SCOPE_AGENT) == g)
                __builtin_amdgcn_s_sleep(2);
        }
    }
    __threadfence();
    __syncthreads();
}

// ---------------------------------------------------------------------------
// K0: kT[b][d][kk] = k[b][kk][d]; also zeroes the grid-barrier counters.
// ---------------------------------------------------------------------------
__global__ __launch_bounds__(256) void kt_kernel(const float* __restrict__ k,
                                                 float* __restrict__ kT,
                                                 unsigned* __restrict__ bar) {
    if (blockIdx.x == 0 && threadIdx.x < 2) bar[threadIdx.x] = 0u;

    __shared__ float tile[64][65];
    const int b  = blockIdx.x >> 3;
    const int k0 = (blockIdx.x & 7) << 6;
    const int t  = threadIdx.x;
    const int r  = t >> 2;                 // 0..63
    const int c0 = (t & 3) << 4;           // 0,16,32,48

    const float* src = k + ((long)(b * 512 + k0 + r)) * 64 + c0;
    #pragma unroll
    for (int m = 0; m < 4; ++m) {
        const float4 v = *(const float4*)(src + 4 * m);
        tile[r][c0 + 4 * m + 0] = v.x;
        tile[r][c0 + 4 * m + 1] = v.y;
        tile[r][c0 + 4 * m + 2] = v.z;
        tile[r][c0 + 4 * m + 3] = v.w;
    }
    __syncthreads();
    float* dst = kT + ((long)b * 64 + r) * 512 + k0 + c0;
    #pragma unroll
    for (int m = 0; m < 4; ++m) {
        float4 v;
        v.x = tile[c0 + 4 * m + 0][r];
        v.y = tile[c0 + 4 * m + 1][r];
        v.z = tile[c0 + 4 * m + 2][r];
        v.w = tile[c0 + 4 * m + 3][r];
        *(float4*)(dst + 4 * m) = v;
    }
}

// ---------------------------------------------------------------------------
// Fused everything. 512 blocks x 512 thr; block = (batch, 8 l-rows).
// Phase A (wave-split, overlapped):
//   waves 4-7: vkc rows (2/wave) -- the 67 MB HBM stream (K1 body, proven)
//   waves 0-3: scores for 8 l-rows; thread owns k-rows {2t,2t+1} via float2
//              kT loads -> q-uniform-load count amortized 2.7x vs R7.
// grid barrier (vkc is cross-block) ->
// Phase B: P2 softmax -> P3 tmp partials -> P4 reduce -> P5 vq.tmp
//          -> P6 residual+LN  (R1's proven 8-row code, tmp in LDS)
// ---------------------------------------------------------------------------
__global__ __launch_bounds__(512, 4) void fused_kernel(
        const float* __restrict__ q,
        const float* __restrict__ kT,
        const float* __restrict__ vk,
        const float* __restrict__ vexp,
        const float* __restrict__ scale_p,
        const float* __restrict__ vq,
        const float* __restrict__ gamma,
        const float* __restrict__ beta,
        float* __restrict__ vkc,
        unsigned* __restrict__ bar,
        float* __restrict__ out) {
    __shared__ float sc[8][512];          // 16 KB
    __shared__ float tp[8][8][64];        // 16 KB
    __shared__ float tmp_s[8][64];        // 2 KB
    __shared__ float attn_s[8][64];       // 2 KB

    const int t = threadIdx.x;
    const int wv = t >> 6;
    const int lane = t & 63;
    const int batch = blockIdx.x >> 6;
    const int l0 = (blockIdx.x & 63) << 3;

    // ==== Phase A ====
    if (wv >= 4) {
        // ---- vkc: 2 rows per wave (K1 body, proven ~6.2 TB/s pattern) ----
        const int n0 = (lane & 15) << 2;
        #pragma unroll
        for (int rr = 0; rr < 2; ++rr) {
            const int unit = (blockIdx.x << 3) + ((wv - 4) << 1) + rr;
            const float ve_reg = vexp[unit * 64 + lane];
            const float* base = vk + (long)unit * 4096;
            float ax = 0.f, ay = 0.f, az = 0.f, aw = 0.f;
            #pragma unroll
            for (int it = 0; it < 16; ++it) {
                const int p = (lane >> 4) + (it << 2);
                const float4 v4 = *(const float4*)(base + p * 64 + n0);
                const float w = __shfl(ve_reg, p, 64);
                ax += v4.x * w; ay += v4.y * w; az += v4.z * w; aw += v4.w * w;
            }
            ax += __shfl_down(ax, 32, 64); ax += __shfl_down(ax, 16, 64);
            ay += __shfl_down(ay, 32, 64); ay += __shfl_down(ay, 16, 64);
            az += __shfl_down(az, 32, 64); az += __shfl_down(az, 16, 64);
            aw += __shfl_down(aw, 32, 64); aw += __shfl_down(aw, 16, 64);
            if ((lane & 48) == 0) {
                float4 r; r.x = ax; r.y = ay; r.z = az; r.w = aw;
                *(float4*)(vkc + unit * 64 + n0) = r;
            }
        }
    } else {
        // ---- scores: thread t owns k-rows {2t, 2t+1}; 8 l-rows ----
        const float scale = scale_p[0];
        const float* qbase = q + (batch * 512 + l0) * 64;      // block-uniform
        const float* ktb = kT + ((long)batch << 15) + (t << 1); // kT[b][0][2t]
        float a0[8], a1[8];
        #pragma unroll
        for (int l = 0; l < 8; ++l) { a0[l] = 0.f; a1[l] = 0.f; }
        #pragma unroll
        for (int dc = 0; dc < 16; ++dc) {
            float2 kv[4];
            #pragma unroll
            for (int j = 0; j < 4; ++j)
                kv[j] = *(const float2*)(ktb + ((dc << 2) + j) * 512);
            #pragma unroll
            for (int l = 0; l < 8; ++l) {
                const float4 qv = ((const float4*)(qbase + l * 64))[dc];
                a0[l] += qv.x * kv[0].x + qv.y * kv[1].x
                       + qv.z * kv[2].x + qv.w * kv[3].x;
                a1[l] += qv.x * kv[0].y + qv.y * kv[1].y
                       + qv.z * kv[2].y + qv.w * kv[3].y;
            }
        }
        #pragma unroll
        for (int l = 0; l < 8; ++l) {
            float2 s2; s2.x = scale * a0[l]; s2.y = scale * a1[l];
            *(float2*)&sc[l][t << 1] = s2;
        }
    }

    grid_barrier(bar, bar + 1);

    // ==== Phase B (R1's proven 8-row pipeline) ====
    // ---- P2: softmax over K=512; wave wv -> row wv ----
    {
        float vv[8]; float mx = -1e30f;
        #pragma unroll
        for (int j = 0; j < 8; ++j) { vv[j] = sc[wv][lane + 64 * j]; mx = fmaxf(mx, vv[j]); }
        #pragma unroll
        for (int off = 32; off; off >>= 1) mx = fmaxf(mx, __shfl_xor(mx, off, 64));
        float s = 0.f;
        #pragma unroll
        for (int j = 0; j < 8; ++j) { vv[j] = __expf(vv[j] - mx); s += vv[j]; }
        #pragma unroll
        for (int off = 32; off; off >>= 1) s += __shfl_xor(s, off, 64);
        const float inv = 1.0f / s;
        #pragma unroll
        for (int j = 0; j < 8; ++j) sc[wv][lane + 64 * j] = vv[j] * inv;
    }
    lds_barrier();

    // ---- P3: tmp[l][n] partials; wave wv covers k in [wv*64, wv*64+64) ----
    {
        const float* vkcb = vkc + batch * 512 * 64;
        const int ksub = lane >> 4;
        const int n0 = (lane & 15) << 2;
        const int kbeg = wv << 6;
        float4 a[8];
        #pragma unroll
        for (int l = 0; l < 8; ++l) { a[l].x = 0.f; a[l].y = 0.f; a[l].z = 0.f; a[l].w = 0.f; }
        #pragma unroll
        for (int i = 0; i < 16; ++i) {
            const int kk = kbeg + (i << 2) + ksub;
            const float4 v4 = *(const float4*)(vkcb + kk * 64 + n0);  // 1 KB/instr
            #pragma unroll
            for (int l = 0; l < 8; ++l) {
                const float w = sc[l][kk];
                a[l].x += w * v4.x; a[l].y += w * v4.y;
                a[l].z += w * v4.z; a[l].w += w * v4.w;
            }
        }
        #pragma unroll
        for (int l = 0; l < 8; ++l) {
            a[l].x += __shfl_down(a[l].x, 32, 64); a[l].x += __shfl_down(a[l].x, 16, 64);
            a[l].y += __shfl_down(a[l].y, 32, 64); a[l].y += __shfl_down(a[l].y, 16, 64);
            a[l].z += __shfl_down(a[l].z, 32, 64); a[l].z += __shfl_down(a[l].z, 16, 64);
            a[l].w += __shfl_down(a[l].w, 32, 64); a[l].w += __shfl_down(a[l].w, 16, 64);
        }
        if (lane < 16) {
            #pragma unroll
            for (int l = 0; l < 8; ++l)
                *(float4*)&tp[wv][l][lane << 2] = a[l];
        }
    }
    lds_barrier();

    // ---- P4: reduce 8 wave partials; wave wv -> row wv (same-wave as P5) --
    {
        float s = tp[0][wv][lane];
        #pragma unroll
        for (int w = 1; w < 8; ++w) s += tp[w][wv][lane];
        tmp_s[wv][lane] = s;
    }
    // tmp_s[wv] produced+consumed by wave wv -> no barrier

    // ---- P5+P6: wave wv -> row l0+wv: attn = vq.tmp -> residual + LN ----
    {
        const int row = batch * 512 + l0 + wv;
        const float* vql = vq + (long)row * 4096;

        float4 v[16];
        #pragma unroll
        for (int it = 0; it < 16; ++it)
            v[it] = *(const float4*)(vql + it * 256 + lane * 4);

        const float qv = q[row * 64 + lane];
        const int n0 = (lane & 15) << 2;
        const float4 t4 = *(const float4*)&tmp_s[wv][n0];

        #pragma unroll
        for (int it = 0; it < 16; ++it) {
            float part = v[it].x * t4.x + v[it].y * t4.y + v[it].z * t4.z + v[it].w * t4.w;
            part += __shfl_down(part, 8, 16);
            part += __shfl_down(part, 4, 16);
            part += __shfl_down(part, 2, 16);
            part += __shfl_down(part, 1, 16);
            if ((lane & 15) == 0) attn_s[wv][it * 4 + (lane >> 4)] = part;
        }
        // attn_s[wv] same-wave -> no barrier

        const float x = qv + attn_s[wv][lane];
        float s1 = x, s2 = x * x;
        #pragma unroll
        for (int off = 32; off; off >>= 1) {
            s1 += __shfl_xor(s1, off, 64);
            s2 += __shfl_xor(s2, off, 64);
        }
        const float mean = s1 * (1.0f / 64.0f);
        const float var = s2 * (1.0f / 64.0f) - mean * mean;
        const float r = rsqrtf(var + 1e-3f);
        out[row * 64 + lane] = (x - mean) * r * gamma[lane] + beta[lane];
    }
}

extern "C" void kernel_launch(void* const* d_in, const int* in_sizes, int n_in,
                              void* d_out, int out_size, void* d_ws, size_t ws_size,
                              hipStream_t stream) {
    const float* q     = (const float*)d_in[0];
    const float* k     = (const float*)d_in[1];
    const float* vq    = (const float*)d_in[2];
    const float* vk    = (const float*)d_in[3];
    const float* vexp  = (const float*)d_in[4];
    const float* scale = (const float*)d_in[5];
    const float* gamma = (const float*)d_in[6];
    const float* beta  = (const float*)d_in[7];
    float* out = (float*)d_out;

    float* vkc = (float*)d_ws;                    // 1 MB
    float* kT  = vkc + 8 * 512 * 64;              // 1 MB
    unsigned* bar = (unsigned*)(kT + 8 * 512 * 64);

    kt_kernel<<<64, 256, 0, stream>>>(k, kT, bar);
    fused_kernel<<<NB, 512, 0, stream>>>(q, kT, vk, vexp, scale, vq,
                                         gamma, beta, vkc, bar, out);
}

// Round 9
// 178.555 us; speedup vs baseline: 2.1049x; 2.1049x over previous
//
#include <hip/hip_runtime.h>

// B=8, L=512, K=512, D=M=N=P=64, all fp32.
// ws: vkc = 1 MB | kT = 1 MB  (kT[b][d][k])

__device__ __forceinline__ void lds_barrier() {
    asm volatile("s_waitcnt lgkmcnt(0)" ::: "memory");
    __builtin_amdgcn_s_barrier();
}

// ---------------------------------------------------------------------------
// K1': vkc (proven ~6.2 TB/s body, 4 rows/block) + blocks 0-63 also emit the
// kT transpose tile (overlapped with the other blocks' vk HBM stream).
// ---------------------------------------------------------------------------
__global__ __launch_bounds__(256) void vkc_kt_kernel(const float* __restrict__ vk,
                                                     const float* __restrict__ vexp,
                                                     const float* __restrict__ k,
                                                     float* __restrict__ vkc,
                                                     float* __restrict__ kT) {
    __shared__ float tile[64][65];

    {   // ---- vkc: wave = b*512 + k row ----
        const int wave = (blockIdx.x << 2) + (threadIdx.x >> 6);
        const int lane = threadIdx.x & 63;
        const float ve_reg = vexp[wave * 64 + lane];
        const int n0 = (lane & 15) << 2;
        const float* base = vk + (long)wave * 4096;

        float ax = 0.f, ay = 0.f, az = 0.f, aw = 0.f;
        #pragma unroll
        for (int it = 0; it < 16; ++it) {
            const int p = (lane >> 4) + (it << 2);
            const float4 v4 = *(const float4*)(base + p * 64 + n0);
            const float w = __shfl(ve_reg, p, 64);
            ax += v4.x * w; ay += v4.y * w; az += v4.z * w; aw += v4.w * w;
        }
        ax += __shfl_down(ax, 32, 64); ax += __shfl_down(ax, 16, 64);
        ay += __shfl_down(ay, 32, 64); ay += __shfl_down(ay, 16, 64);
        az += __shfl_down(az, 32, 64); az += __shfl_down(az, 16, 64);
        aw += __shfl_down(aw, 32, 64); aw += __shfl_down(aw, 16, 64);

        if ((lane & 48) == 0) {
            float4 r; r.x = ax; r.y = ay; r.z = az; r.w = aw;
            *(float4*)(vkc + wave * 64 + n0) = r;
        }
    }

    if (blockIdx.x < 64) {   // ---- kT tile: kT[b][d][kk] = k[b][kk][d] ----
        const int b  = blockIdx.x >> 3;
        const int k0 = (blockIdx.x & 7) << 6;
        const int t  = threadIdx.x;
        const int r  = t >> 2;                 // 0..63
        const int c0 = (t & 3) << 4;           // 0,16,32,48

        const float* src = k + ((long)(b * 512 + k0 + r)) * 64 + c0;
        #pragma unroll
        for (int m = 0; m < 4; ++m) {
            const float4 v = *(const float4*)(src + 4 * m);
            tile[r][c0 + 4 * m + 0] = v.x;
            tile[r][c0 + 4 * m + 1] = v.y;
            tile[r][c0 + 4 * m + 2] = v.z;
            tile[r][c0 + 4 * m + 3] = v.w;
        }
        __syncthreads();
        float* dst = kT + ((long)b * 64 + r) * 512 + k0 + c0;
        #pragma unroll
        for (int m = 0; m < 4; ++m) {
            float4 v;
            v.x = tile[c0 + 4 * m + 0][r];
            v.y = tile[c0 + 4 * m + 1][r];
            v.z = tile[c0 + 4 * m + 2][r];
            v.w = tile[c0 + 4 * m + 3][r];
            *(float4*)(dst + 4 * m) = v;
        }
    }
}

// ---------------------------------------------------------------------------
// Fused scores->out. 512 blocks x 512 thr; block = (batch, 8 l-rows).
// P1 at 24 VMEM/dot (R7 was 32): thread t owns k-row t via coalesced kT
// dword loads (64 -> 8/dot); q float4 loads amortized over 8 l-rows
// (128 -> 16/dot). Phase B = R1's proven 8-row P2-P6 verbatim.
// ---------------------------------------------------------------------------
__global__ __launch_bounds__(512) void score_out_kernel(
        const float* __restrict__ q,
        const float* __restrict__ kT,
        const float* __restrict__ vkc,
        const float* __restrict__ scale_p,
        const float* __restrict__ vq,
        const float* __restrict__ gamma,
        const float* __restrict__ beta,
        float* __restrict__ out) {
    __shared__ float sc[8][512];          // 16 KB
    __shared__ float tp[8][8][64];        // 16 KB
    __shared__ float tmp_s[8][64];        // 2 KB
    __shared__ float attn_s[8][64];       // 2 KB

    const int t = threadIdx.x;
    const int wv = t >> 6;
    const int lane = t & 63;
    const int batch = blockIdx.x >> 6;
    const int l0 = (blockIdx.x & 63) << 3;

    const float scale = scale_p[0];
    const float* qbase = q + (batch * 512 + l0) * 64;   // block-uniform

    // ---- P1: thread t owns k-row t; coalesced kT reads; 8 l-dots ----
    {
        const float* ktb = kT + ((long)batch << 15) + t;   // kT[b][0][t]
        float acc[8];
        #pragma unroll
        for (int l = 0; l < 8; ++l) acc[l] = 0.f;
        #pragma unroll
        for (int dc = 0; dc < 16; ++dc) {
            float kv[4];
            #pragma unroll
            for (int j = 0; j < 4; ++j)
                kv[j] = ktb[((dc << 2) + j) << 9];          // 256 B/wave, coalesced
            #pragma unroll
            for (int l = 0; l < 8; ++l) {
                const float4 qv = ((const float4*)(qbase + l * 64))[dc];
                acc[l] += qv.x * kv[0] + qv.y * kv[1]
                        + qv.z * kv[2] + qv.w * kv[3];
            }
        }
        #pragma unroll
        for (int l = 0; l < 8; ++l) sc[l][t] = scale * acc[l];  // coalesced LDS
    }
    lds_barrier();

    // ---- P2: softmax over K=512; wave wv -> l=wv ----
    {
        float vv[8]; float mx = -1e30f;
        #pragma unroll
        for (int j = 0; j < 8; ++j) { vv[j] = sc[wv][lane + 64 * j]; mx = fmaxf(mx, vv[j]); }
        #pragma unroll
        for (int off = 32; off; off >>= 1) mx = fmaxf(mx, __shfl_xor(mx, off, 64));
        float s = 0.f;
        #pragma unroll
        for (int j = 0; j < 8; ++j) { vv[j] = __expf(vv[j] - mx); s += vv[j]; }
        #pragma unroll
        for (int off = 32; off; off >>= 1) s += __shfl_xor(s, off, 64);
        const float inv = 1.0f / s;
        #pragma unroll
        for (int j = 0; j < 8; ++j) sc[wv][lane + 64 * j] = vv[j] * inv;
    }
    lds_barrier();

    // ---- P3: tmp[l][n] partials; wave wv covers k in [wv*64, +64) ----
    {
        const float* vkcb = vkc + batch * 512 * 64;
        const int ksub = lane >> 4;
        const int n0 = (lane & 15) << 2;
        const int kbeg = wv << 6;
        float4 a[8];
        #pragma unroll
        for (int l = 0; l < 8; ++l) { a[l].x = 0.f; a[l].y = 0.f; a[l].z = 0.f; a[l].w = 0.f; }
        #pragma unroll
        for (int i = 0; i < 16; ++i) {
            const int kk = kbeg + (i << 2) + ksub;
            const float4 v4 = *(const float4*)(vkcb + kk * 64 + n0);  // 1 KB/instr
            #pragma unroll
            for (int l = 0; l < 8; ++l) {
                const float w = sc[l][kk];
                a[l].x += w * v4.x; a[l].y += w * v4.y;
                a[l].z += w * v4.z; a[l].w += w * v4.w;
            }
        }
        #pragma unroll
        for (int l = 0; l < 8; ++l) {
            a[l].x += __shfl_down(a[l].x, 32, 64); a[l].x += __shfl_down(a[l].x, 16, 64);
            a[l].y += __shfl_down(a[l].y, 32, 64); a[l].y += __shfl_down(a[l].y, 16, 64);
            a[l].z += __shfl_down(a[l].z, 32, 64); a[l].z += __shfl_down(a[l].z, 16, 64);
            a[l].w += __shfl_down(a[l].w, 32, 64); a[l].w += __shfl_down(a[l].w, 16, 64);
        }
        if (lane < 16) {
            #pragma unroll
            for (int l = 0; l < 8; ++l)
                *(float4*)&tp[wv][l][lane << 2] = a[l];
        }
    }
    lds_barrier();

    // ---- P4: reduce 8 wave partials; wave wv -> row wv (same-wave as P5) --
    {
        float s = tp[0][wv][lane];
        #pragma unroll
        for (int w = 1; w < 8; ++w) s += tp[w][wv][lane];
        tmp_s[wv][lane] = s;
    }
    // tmp_s[wv] produced+consumed by wave wv -> no barrier

    // ---- P5+P6: wave wv -> row l0+wv: attn = vq.tmp -> residual + LN ----
    {
        const int row = batch * 512 + l0 + wv;
        const float* vql = vq + (long)row * 4096;

        float4 v[16];
        #pragma unroll
        for (int it = 0; it < 16; ++it)
            v[it] = *(const float4*)(vql + it * 256 + lane * 4);

        const float qv = q[row * 64 + lane];
        const int n0 = (lane & 15) << 2;
        const float4 t4 = *(const float4*)&tmp_s[wv][n0];

        #pragma unroll
        for (int it = 0; it < 16; ++it) {
            float part = v[it].x * t4.x + v[it].y * t4.y + v[it].z * t4.z + v[it].w * t4.w;
            part += __shfl_down(part, 8, 16);
            part += __shfl_down(part, 4, 16);
            part += __shfl_down(part, 2, 16);
            part += __shfl_down(part, 1, 16);
            if ((lane & 15) == 0) attn_s[wv][it * 4 + (lane >> 4)] = part;
        }
        // attn_s[wv] same-wave -> no barrier

        const float x = qv + attn_s[wv][lane];
        float s1 = x, s2 = x * x;
        #pragma unroll
        for (int off = 32; off; off >>= 1) {
            s1 += __shfl_xor(s1, off, 64);
            s2 += __shfl_xor(s2, off, 64);
        }
        const float mean = s1 * (1.0f / 64.0f);
        const float var = s2 * (1.0f / 64.0f) - mean * mean;
        const float r = rsqrtf(var + 1e-3f);
        out[row * 64 + lane] = (x - mean) * r * gamma[lane] + beta[lane];
    }
}

extern "C" void kernel_launch(void* const* d_in, const int* in_sizes, int n_in,
                              void* d_out, int out_size, void* d_ws, size_t ws_size,
                              hipStream_t stream) {
    const float* q     = (const float*)d_in[0];
    const float* k     = (const float*)d_in[1];
    const float* vq    = (const float*)d_in[2];
    const float* vk    = (const float*)d_in[3];
    const float* vexp  = (const float*)d_in[4];
    const float* scale = (const float*)d_in[5];
    const float* gamma = (const float*)d_in[6];
    const float* beta  = (const float*)d_in[7];
    float* out = (float*)d_out;

    float* vkc = (float*)d_ws;                 // 1 MB
    float* kT  = vkc + 8 * 512 * 64;           // 1 MB

    vkc_kt_kernel<<<1024, 256, 0, stream>>>(vk, vexp, k, vkc, kT);
    score_out_kernel<<<512, 512, 0, stream>>>(q, kT, vkc, scale, vq, gamma, beta, out);
}

// Round 10
// 178.476 us; speedup vs baseline: 2.1059x; 1.0004x over previous
//
#include <hip/hip_runtime.h>

// B=8, L=512, K=512, D=M=N=P=64, all fp32.
// Main path ws: vkc 1 MB | kT 1 MB | weights 8 MB  (10 MB total)
// Fallback (ws < 10 MB): exact R7 three-kernel structure (2 MB).

__device__ __forceinline__ void lds_barrier() {
    asm volatile("s_waitcnt lgkmcnt(0)" ::: "memory");
    __builtin_amdgcn_s_barrier();
}

// ---------------------------------------------------------------------------
// K0: kT[b][d][kk] = k[b][kk][d].  64 blocks x 256 thr, LDS 64x65 tile.
// ---------------------------------------------------------------------------
__global__ __launch_bounds__(256) void kt_kernel(const float* __restrict__ k,
                                                 float* __restrict__ kT) {
    __shared__ float tile[64][65];
    const int b  = blockIdx.x >> 3;
    const int k0 = (blockIdx.x & 7) << 6;
    const int t  = threadIdx.x;
    const int r  = t >> 2;
    const int c0 = (t & 3) << 4;

    const float* src = k + ((long)(b * 512 + k0 + r)) * 64 + c0;
    #pragma unroll
    for (int m = 0; m < 4; ++m) {
        const float4 v = *(const float4*)(src + 4 * m);
        tile[r][c0 + 4 * m + 0] = v.x;
        tile[r][c0 + 4 * m + 1] = v.y;
        tile[r][c0 + 4 * m + 2] = v.z;
        tile[r][c0 + 4 * m + 3] = v.w;
    }
    __syncthreads();
    float* dst = kT + ((long)b * 64 + r) * 512 + k0 + c0;
    #pragma unroll
    for (int m = 0; m < 4; ++m) {
        float4 v;
        v.x = tile[c0 + 4 * m + 0][r];
        v.y = tile[c0 + 4 * m + 1][r];
        v.z = tile[c0 + 4 * m + 2][r];
        v.w = tile[c0 + 4 * m + 3][r];
        *(float4*)(dst + 4 * m) = v;
    }
}

// ---------------------------------------------------------------------------
// Kernel A: BLOCK-split TLP. 1024 blocks x 512 thr.
//   blocks [0,512):   pure vkc HBM streamers (8 rows, 1/wave; proven K1 body)
//   blocks [512,1024): scores (8 l-rows; R9's lean kT P1) + softmax -> weights
// Round-robin dispatch gives each CU 2 streamer + 2 score blocks co-resident:
// the vk HBM stream overlaps the L2/VALU score work ACROSS blocks (no shared
// per-wave vmcnt chain -- the R2/R3 in-order-vmcnt poison doesn't apply).
// ---------------------------------------------------------------------------
__global__ __launch_bounds__(512) void vkc_score_kernel(
        const float* __restrict__ q,
        const float* __restrict__ kT,
        const float* __restrict__ vk,
        const float* __restrict__ vexp,
        const float* __restrict__ scale_p,
        float* __restrict__ vkc,
        float* __restrict__ weights_g) {
    __shared__ float sc[8][512];          // 16 KB (score blocks only)

    const int t = threadIdx.x;
    const int wv = t >> 6;
    const int lane = t & 63;

    if (blockIdx.x < 512) {
        // ---- vkc: wave wv -> row unit = blockIdx*8 + wv ----
        const int unit = (blockIdx.x << 3) + wv;
        const float ve_reg = vexp[unit * 64 + lane];
        const int n0 = (lane & 15) << 2;
        const float* base = vk + (long)unit * 4096;

        float ax = 0.f, ay = 0.f, az = 0.f, aw = 0.f;
        #pragma unroll
        for (int it = 0; it < 16; ++it) {
            const int p = (lane >> 4) + (it << 2);
            const float4 v4 = *(const float4*)(base + p * 64 + n0);
            const float w = __shfl(ve_reg, p, 64);
            ax += v4.x * w; ay += v4.y * w; az += v4.z * w; aw += v4.w * w;
        }
        ax += __shfl_down(ax, 32, 64); ax += __shfl_down(ax, 16, 64);
        ay += __shfl_down(ay, 32, 64); ay += __shfl_down(ay, 16, 64);
        az += __shfl_down(az, 32, 64); az += __shfl_down(az, 16, 64);
        aw += __shfl_down(aw, 32, 64); aw += __shfl_down(aw, 16, 64);

        if ((lane & 48) == 0) {
            float4 r; r.x = ax; r.y = ay; r.z = az; r.w = aw;
            *(float4*)(vkc + unit * 64 + n0) = r;
        }
        return;
    }

    // ---- score block: (batch, 8 l-rows) ----
    const int bb = blockIdx.x - 512;
    const int batch = bb >> 6;
    const int l0 = (bb & 63) << 3;
    const float scale = scale_p[0];
    const float* qbase = q + (batch * 512 + l0) * 64;   // block-uniform

    {   // P1 (R9's lean layout, correctness-proven): thread t owns k-row t
        const float* ktb = kT + ((long)batch << 15) + t;   // kT[b][0][t]
        float acc[8];
        #pragma unroll
        for (int l = 0; l < 8; ++l) acc[l] = 0.f;
        #pragma unroll
        for (int dc = 0; dc < 16; ++dc) {
            float kv[4];
            #pragma unroll
            for (int j = 0; j < 4; ++j)
                kv[j] = ktb[((dc << 2) + j) << 9];          // coalesced
            #pragma unroll
            for (int l = 0; l < 8; ++l) {
                const float4 qv = ((const float4*)(qbase + l * 64))[dc];
                acc[l] += qv.x * kv[0] + qv.y * kv[1]
                        + qv.z * kv[2] + qv.w * kv[3];
            }
        }
        #pragma unroll
        for (int l = 0; l < 8; ++l) sc[l][t] = scale * acc[l];
    }
    lds_barrier();

    {   // P2: softmax over K=512; wave wv -> row l0+wv; weights to global
        float vv[8]; float mx = -1e30f;
        #pragma unroll
        for (int j = 0; j < 8; ++j) { vv[j] = sc[wv][lane + 64 * j]; mx = fmaxf(mx, vv[j]); }
        #pragma unroll
        for (int off = 32; off; off >>= 1) mx = fmaxf(mx, __shfl_xor(mx, off, 64));
        float s = 0.f;
        #pragma unroll
        for (int j = 0; j < 8; ++j) { vv[j] = __expf(vv[j] - mx); s += vv[j]; }
        #pragma unroll
        for (int off = 32; off; off >>= 1) s += __shfl_xor(s, off, 64);
        const float inv = 1.0f / s;
        float* wrow = weights_g + (long)(batch * 512 + l0 + wv) * 512;
        #pragma unroll
        for (int j = 0; j < 8; ++j) wrow[lane + 64 * j] = vv[j] * inv;  // coalesced
    }
}

// ---------------------------------------------------------------------------
// Kernel B (R5's proven tmp_out_kernel, verbatim): stage weights (8 KB) ->
// LDS, then P3 tmp partials (+ vq prefetch) -> P4 reduce -> P5 vq.tmp
// -> P6 residual + LN -> out.  1024 blocks x 512 thr, 4 l-rows/block.
// ---------------------------------------------------------------------------
__global__ __launch_bounds__(512) void tmp_out_kernel(
        const float* __restrict__ q,
        const float* __restrict__ vkc,
        const float* __restrict__ weights_g,
        const float* __restrict__ vq,
        const float* __restrict__ gamma,
        const float* __restrict__ beta,
        float* __restrict__ out) {
    __shared__ float sc[4][512];          // 8 KB
    __shared__ float tp[8][4][64];        // 8 KB
    __shared__ float tmp_s[4][64];        // 1 KB
    __shared__ float attn_s[4][64];       // 1 KB

    const int t = threadIdx.x;
    const int wv = t >> 6;
    const int lane = t & 63;
    const int batch = blockIdx.x >> 7;
    const int l0 = (blockIdx.x & 127) << 2;

    const float qres = q[(batch * 512 + l0 + (wv & 3)) * 64 + lane];

    {   // stage the block's 4 weight rows into LDS (coalesced float4)
        const float4 wchunk = *(const float4*)(weights_g +
                                (long)(batch * 512 + l0) * 512 + t * 4);
        *(float4*)(&sc[0][0] + t * 4) = wchunk;
    }
    lds_barrier();

    const int row = batch * 512 + l0 + (wv & 3);
    const int half = wv >> 2;
    const float* vql = vq + (long)row * 4096 + half * 2048;
    float4 v[8];
    {
        const float* vkcb = vkc + batch * 512 * 64;
        const int ksub = lane >> 4;
        const int n0 = (lane & 15) << 2;
        const int kbeg = wv << 6;
        float4 a[4];
        #pragma unroll
        for (int l = 0; l < 4; ++l) { a[l].x = 0.f; a[l].y = 0.f; a[l].z = 0.f; a[l].w = 0.f; }
        #pragma unroll
        for (int i = 0; i < 16; ++i) {
            if (i < 8) v[i] = *(const float4*)(vql + i * 256 + lane * 4);
            const int kk = kbeg + (i << 2) + ksub;
            const float4 v4 = *(const float4*)(vkcb + kk * 64 + n0);
            #pragma unroll
            for (int l = 0; l < 4; ++l) {
                const float w = sc[l][kk];
                a[l].x += w * v4.x; a[l].y += w * v4.y;
                a[l].z += w * v4.z; a[l].w += w * v4.w;
            }
        }
        #pragma unroll
        for (int l = 0; l < 4; ++l) {
            a[l].x += __shfl_down(a[l].x, 32, 64); a[l].x += __shfl_down(a[l].x, 16, 64);
            a[l].y += __shfl_down(a[l].y, 32, 64); a[l].y += __shfl_down(a[l].y, 16, 64);
            a[l].z += __shfl_down(a[l].z, 32, 64); a[l].z += __shfl_down(a[l].z, 16, 64);
            a[l].w += __shfl_down(a[l].w, 32, 64); a[l].w += __shfl_down(a[l].w, 16, 64);
        }
        if (lane < 16) {
            #pragma unroll
            for (int l = 0; l < 4; ++l)
                *(float4*)&tp[wv][l][lane << 2] = a[l];
        }
    }
    lds_barrier();

    if (t < 256) {
        const int l = t >> 6, n = t & 63;
        float s = tp[0][l][n];
        #pragma unroll
        for (int w = 1; w < 8; ++w) s += tp[w][l][n];
        tmp_s[l][n] = s;
    }
    lds_barrier();

    {
        const int n0 = (lane & 15) << 2;
        const float4 t4 = *(const float4*)&tmp_s[wv & 3][n0];
        #pragma unroll
        for (int j = 0; j < 8; ++j) {
            float part = v[j].x * t4.x + v[j].y * t4.y + v[j].z * t4.z + v[j].w * t4.w;
            part += __shfl_down(part, 8, 16);
            part += __shfl_down(part, 4, 16);
            part += __shfl_down(part, 2, 16);
            part += __shfl_down(part, 1, 16);
            if ((lane & 15) == 0)
                attn_s[wv & 3][half * 32 + j * 4 + (lane >> 4)] = part;
        }
    }
    lds_barrier();

    if (t < 256) {
        const int orow = batch * 512 + l0 + wv;
        const float x = qres + attn_s[wv][lane];
        float s1 = x, s2 = x * x;
        #pragma unroll
        for (int off = 32; off; off >>= 1) {
            s1 += __shfl_xor(s1, off, 64);
            s2 += __shfl_xor(s2, off, 64);
        }
        const float mean = s1 * (1.0f / 64.0f);
        const float var = s2 * (1.0f / 64.0f) - mean * mean;
        const float r = rsqrtf(var + 1e-3f);
        out[orow * 64 + lane] = (x - mean) * r * gamma[lane] + beta[lane];
    }
}

// ---------------------------------------------------------------------------
// Fallback path (ws < 10 MB): exact R7 structure (best measured, 174.0 us).
// ---------------------------------------------------------------------------
__global__ __launch_bounds__(256) void vkc_kernel(const float* __restrict__ vk,
                                                  const float* __restrict__ vexp,
                                                  float* __restrict__ vkc) {
    const int wave = (blockIdx.x << 2) + (threadIdx.x >> 6);
    const int lane = threadIdx.x & 63;
    const float ve_reg = vexp[wave * 64 + lane];
    const int n0 = (lane & 15) << 2;
    const float* base = vk + (long)wave * 4096;

    float ax = 0.f, ay = 0.f, az = 0.f, aw = 0.f;
    #pragma unroll
    for (int it = 0; it < 16; ++it) {
        const int p = (lane >> 4) + (it << 2);
        const float4 v4 = *(const float4*)(base + p * 64 + n0);
        const float w = __shfl(ve_reg, p, 64);
        ax += v4.x * w; ay += v4.y * w; az += v4.z * w; aw += v4.w * w;
    }
    ax += __shfl_down(ax, 32, 64); ax += __shfl_down(ax, 16, 64);
    ay += __shfl_down(ay, 32, 64); ay += __shfl_down(ay, 16, 64);
    az += __shfl_down(az, 32, 64); az += __shfl_down(az, 16, 64);
    aw += __shfl_down(aw, 32, 64); aw += __shfl_down(aw, 16, 64);

    if ((lane & 48) == 0) {
        float4 r; r.x = ax; r.y = ay; r.z = az; r.w = aw;
        *(float4*)(vkc + wave * 64 + n0) = r;
    }
}

__global__ __launch_bounds__(512) void score_out_kernel(
        const float* __restrict__ q,
        const float* __restrict__ kT,
        const float* __restrict__ vkc,
        const float* __restrict__ scale_p,
        const float* __restrict__ vq,
        const float* __restrict__ gamma,
        const float* __restrict__ beta,
        float* __restrict__ out) {
    __shared__ float sc[4][512];
    __shared__ float tp[8][4][64];
    __shared__ float tmp_s[4][64];
    __shared__ float attn_s[4][64];

    const int t = threadIdx.x;
    const int wv = t >> 6;
    const int lane = t & 63;
    const int batch = blockIdx.x >> 7;
    const int l0 = (blockIdx.x & 127) << 2;

    const float scale = scale_p[0];
    const int ksub = lane >> 4;
    const int n0 = (lane & 15) << 2;
    const float qres = q[(batch * 512 + l0 + (wv & 3)) * 64 + lane];
    const float* qbase = q + (batch * 512 + l0) * 64;

    {
        const float* ktb = kT + (long)batch * 64 * 512 + t;
        float acc0 = 0.f, acc1 = 0.f, acc2 = 0.f, acc3 = 0.f;
        #pragma unroll
        for (int dc4 = 0; dc4 < 16; ++dc4) {
            const float4 qv0 = ((const float4*)(qbase +   0))[dc4];
            const float4 qv1 = ((const float4*)(qbase +  64))[dc4];
            const float4 qv2 = ((const float4*)(qbase + 128))[dc4];
            const float4 qv3 = ((const float4*)(qbase + 192))[dc4];
            const float k0v = ktb[(dc4 * 4 + 0) * 512];
            const float k1v = ktb[(dc4 * 4 + 1) * 512];
            const float k2v = ktb[(dc4 * 4 + 2) * 512];
            const float k3v = ktb[(dc4 * 4 + 3) * 512];
            acc0 += qv0.x * k0v + qv0.y * k1v + qv0.z * k2v + qv0.w * k3v;
            acc1 += qv1.x * k0v + qv1.y * k1v + qv1.z * k2v + qv1.w * k3v;
            acc2 += qv2.x * k0v + qv2.y * k1v + qv2.z * k2v + qv2.w * k3v;
            acc3 += qv3.x * k0v + qv3.y * k1v + qv3.z * k2v + qv3.w * k3v;
        }
        sc[0][t] = scale * acc0;
        sc[1][t] = scale * acc1;
        sc[2][t] = scale * acc2;
        sc[3][t] = scale * acc3;
    }
    lds_barrier();

    if (wv < 4) {
        float vv[8]; float mx = -1e30f;
        #pragma unroll
        for (int j = 0; j < 8; ++j) { vv[j] = sc[wv][lane + 64 * j]; mx = fmaxf(mx, vv[j]); }
        #pragma unroll
        for (int off = 32; off; off >>= 1) mx = fmaxf(mx, __shfl_xor(mx, off, 64));
        float s = 0.f;
        #pragma unroll
        for (int j = 0; j < 8; ++j) { vv[j] = __expf(vv[j] - mx); s += vv[j]; }
        #pragma unroll
        for (int off = 32; off; off >>= 1) s += __shfl_xor(s, off, 64);
        const float inv = 1.0f / s;
        #pragma unroll
        for (int j = 0; j < 8; ++j) sc[wv][lane + 64 * j] = vv[j] * inv;
    }
    lds_barrier();

    const int row = batch * 512 + l0 + (wv & 3);
    const int half = wv >> 2;
    const float* vql = vq + (long)row * 4096 + half * 2048;
    float4 v[8];
    {
        const float* vkcb = vkc + batch * 512 * 64;
        const int kbeg = wv << 6;
        float4 a[4];
        #pragma unroll
        for (int l = 0; l < 4; ++l) { a[l].x = 0.f; a[l].y = 0.f; a[l].z = 0.f; a[l].w = 0.f; }
        #pragma unroll
        for (int i = 0; i < 16; ++i) {
            if (i < 8) v[i] = *(const float4*)(vql + i * 256 + lane * 4);
            const int kk = kbeg + (i << 2) + ksub;
            const float4 v4 = *(const float4*)(vkcb + kk * 64 + n0);
            #pragma unroll
            for (int l = 0; l < 4; ++l) {
                const float w = sc[l][kk];
                a[l].x += w * v4.x; a[l].y += w * v4.y;
                a[l].z += w * v4.z; a[l].w += w * v4.w;
            }
        }
        #pragma unroll
        for (int l = 0; l < 4; ++l) {
            a[l].x += __shfl_down(a[l].x, 32, 64); a[l].x += __shfl_down(a[l].x, 16, 64);
            a[l].y += __shfl_down(a[l].y, 32, 64); a[l].y += __shfl_down(a[l].y, 16, 64);
            a[l].z += __shfl_down(a[l].z, 32, 64); a[l].z += __shfl_down(a[l].z, 16, 64);
            a[l].w += __shfl_down(a[l].w, 32, 64); a[l].w += __shfl_down(a[l].w, 16, 64);
        }
        if (lane < 16) {
            #pragma unroll
            for (int l = 0; l < 4; ++l)
                *(float4*)&tp[wv][l][lane << 2] = a[l];
        }
    }
    lds_barrier();

    if (t < 256) {
        const int l = t >> 6, n = t & 63;
        float s = tp[0][l][n];
        #pragma unroll
        for (int w = 1; w < 8; ++w) s += tp[w][l][n];
        tmp_s[l][n] = s;
    }
    lds_barrier();

    {
        const float4 t4 = *(const float4*)&tmp_s[wv & 3][n0];
        #pragma unroll
        for (int j = 0; j < 8; ++j) {
            float part = v[j].x * t4.x + v[j].y * t4.y + v[j].z * t4.z + v[j].w * t4.w;
            part += __shfl_down(part, 8, 16);
            part += __shfl_down(part, 4, 16);
            part += __shfl_down(part, 2, 16);
            part += __shfl_down(part, 1, 16);
            if ((lane & 15) == 0)
                attn_s[wv & 3][half * 32 + j * 4 + (lane >> 4)] = part;
        }
    }
    lds_barrier();

    if (t < 256) {
        const int orow = batch * 512 + l0 + wv;
        const float x = qres + attn_s[wv][lane];
        float s1 = x, s2 = x * x;
        #pragma unroll
        for (int off = 32; off; off >>= 1) {
            s1 += __shfl_xor(s1, off, 64);
            s2 += __shfl_xor(s2, off, 64);
        }
        const float mean = s1 * (1.0f / 64.0f);
        const float var = s2 * (1.0f / 64.0f) - mean * mean;
        const float r = rsqrtf(var + 1e-3f);
        out[orow * 64 + lane] = (x - mean) * r * gamma[lane] + beta[lane];
    }
}

extern "C" void kernel_launch(void* const* d_in, const int* in_sizes, int n_in,
                              void* d_out, int out_size, void* d_ws, size_t ws_size,
                              hipStream_t stream) {
    const float* q     = (const float*)d_in[0];
    const float* k     = (const float*)d_in[1];
    const float* vq    = (const float*)d_in[2];
    const float* vk    = (const float*)d_in[3];
    const float* vexp  = (const float*)d_in[4];
    const float* scale = (const float*)d_in[5];
    const float* gamma = (const float*)d_in[6];
    const float* beta  = (const float*)d_in[7];
    float* out = (float*)d_out;

    float* vkc = (float*)d_ws;                    // 1 MB
    float* kT  = vkc + 8 * 512 * 64;              // 1 MB
    float* weights = kT + 8 * 512 * 64;           // 8 MB

    const size_t need = (size_t)(2 * 8 * 512 * 64 + 8 * 512 * 512) * sizeof(float);
    if (ws_size >= need) {
        kt_kernel<<<64, 256, 0, stream>>>(k, kT);
        vkc_score_kernel<<<1024, 512, 0, stream>>>(q, kT, vk, vexp, scale,
                                                   vkc, weights);
        tmp_out_kernel<<<1024, 512, 0, stream>>>(q, vkc, weights, vq,
                                                 gamma, beta, out);
    } else {
        kt_kernel<<<64, 256, 0, stream>>>(k, kT);
        vkc_kernel<<<1024, 256, 0, stream>>>(vk, vexp, vkc);
        score_out_kernel<<<512, 512, 0, stream>>>(q, kT, vkc, scale, vq,
                                                  gamma, beta, out);
    }
}

// Round 12
// 171.745 us; speedup vs baseline: 2.1884x; 1.0392x over previous
//
#include <hip/hip_runtime.h>

// B=8, L=512, K=512, D=M=N=P=64, all fp32.
// ws: vkc = 1 MB | kT = 1 MB  (kT[b][d][k])
// Structure: 2 launches.
//   K1': vkc (67 MB vk HBM stream) + folded kT transpose (blocks 0-63)
//   K2 : R7's score_out (lean kT P1 -> softmax -> tmp -> vq.tmp -> res+LN)

__device__ __forceinline__ void lds_barrier() {
    asm volatile("s_waitcnt lgkmcnt(0)" ::: "memory");
    __builtin_amdgcn_s_barrier();
}

// ---------------------------------------------------------------------------
// K1': vkc (proven ~6.2 TB/s body, 4 rows/block) + blocks 0-63 also emit the
// kT transpose tile (rides under the other blocks' vk HBM stream).
// ---------------------------------------------------------------------------
__global__ __launch_bounds__(256) void vkc_kt_kernel(const float* __restrict__ vk,
                                                     const float* __restrict__ vexp,
                                                     const float* __restrict__ k,
                                                     float* __restrict__ vkc,
                                                     float* __restrict__ kT) {
    __shared__ float tile[64][65];

    {   // ---- vkc: wave = b*512 + k row ----
        const int wave = (blockIdx.x << 2) + (threadIdx.x >> 6);
        const int lane = threadIdx.x & 63;
        const float ve_reg = vexp[wave * 64 + lane];
        const int n0 = (lane & 15) << 2;
        const float* base = vk + (long)wave * 4096;

        float ax = 0.f, ay = 0.f, az = 0.f, aw = 0.f;
        #pragma unroll
        for (int it = 0; it < 16; ++it) {
            const int p = (lane >> 4) + (it << 2);
            const float4 v4 = *(const float4*)(base + p * 64 + n0);
            const float w = __shfl(ve_reg, p, 64);
            ax += v4.x * w; ay += v4.y * w; az += v4.z * w; aw += v4.w * w;
        }
        ax += __shfl_down(ax, 32, 64); ax += __shfl_down(ax, 16, 64);
        ay += __shfl_down(ay, 32, 64); ay += __shfl_down(ay, 16, 64);
        az += __shfl_down(az, 32, 64); az += __shfl_down(az, 16, 64);
        aw += __shfl_down(aw, 32, 64); aw += __shfl_down(aw, 16, 64);

        if ((lane & 48) == 0) {
            float4 r; r.x = ax; r.y = ay; r.z = az; r.w = aw;
            *(float4*)(vkc + wave * 64 + n0) = r;
        }
    }

    if (blockIdx.x < 64) {   // ---- kT tile: kT[b][d][kk] = k[b][kk][d] ----
        const int b  = blockIdx.x >> 3;
        const int k0 = (blockIdx.x & 7) << 6;
        const int t  = threadIdx.x;
        const int r  = t >> 2;                 // 0..63
        const int c0 = (t & 3) << 4;           // 0,16,32,48

        const float* src = k + ((long)(b * 512 + k0 + r)) * 64 + c0;
        #pragma unroll
        for (int m = 0; m < 4; ++m) {
            const float4 v = *(const float4*)(src + 4 * m);
            tile[r][c0 + 4 * m + 0] = v.x;
            tile[r][c0 + 4 * m + 1] = v.y;
            tile[r][c0 + 4 * m + 2] = v.z;
            tile[r][c0 + 4 * m + 3] = v.w;
        }
        __syncthreads();
        float* dst = kT + ((long)b * 64 + r) * 512 + k0 + c0;
        #pragma unroll
        for (int m = 0; m < 4; ++m) {
            float4 v;
            v.x = tile[c0 + 4 * m + 0][r];
            v.y = tile[c0 + 4 * m + 1][r];
            v.z = tile[c0 + 4 * m + 2][r];
            v.w = tile[c0 + 4 * m + 3][r];
            *(float4*)(dst + 4 * m) = v;
        }
    }
}

// ---------------------------------------------------------------------------
// K2 (R7 verbatim -- fastest measured): 1024 blocks x 512 thr; block =
// (batch, 4 l-rows). P1 via kT (thread t owns k-row t, coalesced dword
// loads); P2 softmax; P3 tmp partials + interleaved vq prefetch; P4 reduce;
// P5 vq.tmp partial dots; P6 residual + LN.
// ---------------------------------------------------------------------------
__global__ __launch_bounds__(512) void score_out_kernel(
        const float* __restrict__ q,
        const float* __restrict__ kT,
        const float* __restrict__ vkc,
        const float* __restrict__ scale_p,
        const float* __restrict__ vq,
        const float* __restrict__ gamma,
        const float* __restrict__ beta,
        float* __restrict__ out) {
    __shared__ float sc[4][512];          // 8 KB
    __shared__ float tp[8][4][64];        // 8 KB
    __shared__ float tmp_s[4][64];        // 1 KB
    __shared__ float attn_s[4][64];       // 1 KB

    const int t = threadIdx.x;
    const int wv = t >> 6;
    const int lane = t & 63;
    const int batch = blockIdx.x >> 7;
    const int l0 = (blockIdx.x & 127) << 2;

    const float scale = scale_p[0];
    const int ksub = lane >> 4;
    const int n0 = (lane & 15) << 2;
    const float qres = q[(batch * 512 + l0 + (wv & 3)) * 64 + lane];
    const float* qbase = q + (batch * 512 + l0) * 64;

    // ---- P1: scores via kT; thread t owns k-row t; coalesced kT reads ----
    {
        const float* ktb = kT + (long)batch * 64 * 512 + t;
        float acc0 = 0.f, acc1 = 0.f, acc2 = 0.f, acc3 = 0.f;
        #pragma unroll
        for (int dc4 = 0; dc4 < 16; ++dc4) {
            const float4 qv0 = ((const float4*)(qbase +   0))[dc4];
            const float4 qv1 = ((const float4*)(qbase +  64))[dc4];
            const float4 qv2 = ((const float4*)(qbase + 128))[dc4];
            const float4 qv3 = ((const float4*)(qbase + 192))[dc4];
            const float k0v = ktb[(dc4 * 4 + 0) * 512];   // 256 B/wave, coalesced
            const float k1v = ktb[(dc4 * 4 + 1) * 512];
            const float k2v = ktb[(dc4 * 4 + 2) * 512];
            const float k3v = ktb[(dc4 * 4 + 3) * 512];
            acc0 += qv0.x * k0v + qv0.y * k1v + qv0.z * k2v + qv0.w * k3v;
            acc1 += qv1.x * k0v + qv1.y * k1v + qv1.z * k2v + qv1.w * k3v;
            acc2 += qv2.x * k0v + qv2.y * k1v + qv2.z * k2v + qv2.w * k3v;
            acc3 += qv3.x * k0v + qv3.y * k1v + qv3.z * k2v + qv3.w * k3v;
        }
        sc[0][t] = scale * acc0;
        sc[1][t] = scale * acc1;
        sc[2][t] = scale * acc2;
        sc[3][t] = scale * acc3;
    }
    lds_barrier();

    // ---- P2: softmax over K=512; wave wv (<4) -> row wv ----
    if (wv < 4) {
        float vv[8]; float mx = -1e30f;
        #pragma unroll
        for (int j = 0; j < 8; ++j) { vv[j] = sc[wv][lane + 64 * j]; mx = fmaxf(mx, vv[j]); }
        #pragma unroll
        for (int off = 32; off; off >>= 1) mx = fmaxf(mx, __shfl_xor(mx, off, 64));
        float s = 0.f;
        #pragma unroll
        for (int j = 0; j < 8; ++j) { vv[j] = __expf(vv[j] - mx); s += vv[j]; }
        #pragma unroll
        for (int off = 32; off; off >>= 1) s += __shfl_xor(s, off, 64);
        const float inv = 1.0f / s;
        #pragma unroll
        for (int j = 0; j < 8; ++j) sc[wv][lane + 64 * j] = vv[j] * inv;
    }
    lds_barrier();

    // ---- P3: tmp partials over this wave's 64 k; vq prefetch interleaved ---
    const int row = batch * 512 + l0 + (wv & 3);
    const int half = wv >> 2;
    const float* vql = vq + (long)row * 4096 + half * 2048;
    float4 v[8];
    {
        const float* vkcb = vkc + batch * 512 * 64;
        const int kbeg = wv << 6;
        float4 a[4];
        #pragma unroll
        for (int l = 0; l < 4; ++l) { a[l].x = 0.f; a[l].y = 0.f; a[l].z = 0.f; a[l].w = 0.f; }
        #pragma unroll
        for (int i = 0; i < 16; ++i) {
            if (i < 8) v[i] = *(const float4*)(vql + i * 256 + lane * 4);
            const int kk = kbeg + (i << 2) + ksub;
            const float4 v4 = *(const float4*)(vkcb + kk * 64 + n0);
            #pragma unroll
            for (int l = 0; l < 4; ++l) {
                const float w = sc[l][kk];
                a[l].x += w * v4.x; a[l].y += w * v4.y;
                a[l].z += w * v4.z; a[l].w += w * v4.w;
            }
        }
        #pragma unroll
        for (int l = 0; l < 4; ++l) {
            a[l].x += __shfl_down(a[l].x, 32, 64); a[l].x += __shfl_down(a[l].x, 16, 64);
            a[l].y += __shfl_down(a[l].y, 32, 64); a[l].y += __shfl_down(a[l].y, 16, 64);
            a[l].z += __shfl_down(a[l].z, 32, 64); a[l].z += __shfl_down(a[l].z, 16, 64);
            a[l].w += __shfl_down(a[l].w, 32, 64); a[l].w += __shfl_down(a[l].w, 16, 64);
        }
        if (lane < 16) {
            #pragma unroll
            for (int l = 0; l < 4; ++l)
                *(float4*)&tp[wv][l][lane << 2] = a[l];
        }
    }
    lds_barrier();

    // ---- P4: reduce 8 wave partials into tmp_s ----
    if (t < 256) {
        const int l = t >> 6, n = t & 63;
        float s = tp[0][l][n];
        #pragma unroll
        for (int w = 1; w < 8; ++w) s += tp[w][l][n];
        tmp_s[l][n] = s;
    }
    lds_barrier();

    // ---- P5: wave wv -> row l0+(wv&3), M-half (wv>>2): 32 of 64 dots ----
    {
        const float4 t4 = *(const float4*)&tmp_s[wv & 3][n0];
        #pragma unroll
        for (int j = 0; j < 8; ++j) {
            float part = v[j].x * t4.x + v[j].y * t4.y + v[j].z * t4.z + v[j].w * t4.w;
            part += __shfl_down(part, 8, 16);
            part += __shfl_down(part, 4, 16);
            part += __shfl_down(part, 2, 16);
            part += __shfl_down(part, 1, 16);
            if ((lane & 15) == 0)
                attn_s[wv & 3][half * 32 + j * 4 + (lane >> 4)] = part;
        }
    }
    lds_barrier();

    // ---- P6: waves 0-3: row l0+wv: residual + LN -> out ----
    if (t < 256) {
        const int orow = batch * 512 + l0 + wv;
        const float x = qres + attn_s[wv][lane];
        float s1 = x, s2 = x * x;
        #pragma unroll
        for (int off = 32; off; off >>= 1) {
            s1 += __shfl_xor(s1, off, 64);
            s2 += __shfl_xor(s2, off, 64);
        }
        const float mean = s1 * (1.0f / 64.0f);
        const float var = s2 * (1.0f / 64.0f) - mean * mean;
        const float r = rsqrtf(var + 1e-3f);
        out[orow * 64 + lane] = (x - mean) * r * gamma[lane] + beta[lane];
    }
}

extern "C" void kernel_launch(void* const* d_in, const int* in_sizes, int n_in,
                              void* d_out, int out_size, void* d_ws, size_t ws_size,
                              hipStream_t stream) {
    const float* q     = (const float*)d_in[0];
    const float* k     = (const float*)d_in[1];
    const float* vq    = (const float*)d_in[2];
    const float* vk    = (const float*)d_in[3];
    const float* vexp  = (const float*)d_in[4];
    const float* scale = (const float*)d_in[5];
    const float* gamma = (const float*)d_in[6];
    const float* beta  = (const float*)d_in[7];
    float* out = (float*)d_out;

    float* vkc = (float*)d_ws;                 // 1 MB
    float* kT  = vkc + 8 * 512 * 64;           // 1 MB

    vkc_kt_kernel<<<1024, 256, 0, stream>>>(vk, vexp, k, vkc, kT);
    score_out_kernel<<<1024, 512, 0, stream>>>(q, kT, vkc, scale, vq, gamma, beta, out);
}